// Round 5
// baseline (1081.983 us; speedup 1.0000x reference)
//
#include <hip/hip_runtime.h>

#define NU 100000
#define NI 200000
#define NE 1000000
#define NB 4096
#define NBKT 196
#define NTI (NI / 16)
#define NTU (NU / 16)

typedef __attribute__((ext_vector_type(8))) short bf16x8;
typedef __attribute__((ext_vector_type(4))) float f32x4;
typedef __attribute__((ext_vector_type(8))) unsigned short u16x8;

static __device__ __forceinline__ short f2bf(float f) {
  unsigned u = __builtin_bit_cast(unsigned, f);
  unsigned r = (u + 0x7fffu + ((u >> 16) & 1u)) >> 16;
  return (short)r;
}
static __device__ __forceinline__ float bf2f(unsigned short u) {
  return __builtin_bit_cast(float, ((unsigned)u) << 16);
}

// ================= degree histogram =================
__global__ __launch_bounds__(256) void hist_kernel(const int* __restrict__ src,
                                                   const int* __restrict__ dst,
                                                   int* __restrict__ cnt_u,
                                                   int* __restrict__ cnt_i) {
  int e = blockIdx.x * 256 + threadIdx.x;
  if (e < NE) {
    atomicAdd(&cnt_u[src[e]], 1);
    atomicAdd(&cnt_i[dst[e]], 1);
  }
}

// ================= exclusive scan (3-pass) =================
__global__ __launch_bounds__(256) void scan_blocks(const int* __restrict__ cnt,
                                                   int* __restrict__ ofs,
                                                   int* __restrict__ partials, int n) {
  __shared__ int sm[256];
  int i = blockIdx.x * 256 + threadIdx.x;
  int v = (i < n) ? cnt[i] : 0;
  sm[threadIdx.x] = v;
  __syncthreads();
  for (int off = 1; off < 256; off <<= 1) {
    int t = (threadIdx.x >= off) ? sm[threadIdx.x - off] : 0;
    __syncthreads();
    sm[threadIdx.x] += t;
    __syncthreads();
  }
  if (i < n) ofs[i] = sm[threadIdx.x] - v;
  if (threadIdx.x == 255) partials[blockIdx.x] = sm[255];
}

__global__ __launch_bounds__(1024) void scan_partials(int* __restrict__ partials, int nblocks) {
  __shared__ int sm[1024];
  int v = (threadIdx.x < nblocks) ? partials[threadIdx.x] : 0;
  sm[threadIdx.x] = v;
  __syncthreads();
  for (int off = 1; off < 1024; off <<= 1) {
    int t = (threadIdx.x >= off) ? sm[threadIdx.x - off] : 0;
    __syncthreads();
    sm[threadIdx.x] += t;
    __syncthreads();
  }
  if (threadIdx.x < nblocks) partials[threadIdx.x] = sm[threadIdx.x] - v;
}

__global__ __launch_bounds__(256) void add_offsets(int* __restrict__ ofs,
                                                   const int* __restrict__ partials,
                                                   int n, int total) {
  int i = blockIdx.x * 256 + threadIdx.x;
  if (i < n) ofs[i] += partials[i / 256];
  if (i == 0) ofs[n] = total;
}

__global__ __launch_bounds__(256) void copy_int(const int* __restrict__ a, int* __restrict__ b, int n) {
  int i = blockIdx.x * 256 + threadIdx.x;
  if (i < n) b[i] = a[i];
}

__global__ __launch_bounds__(256) void init_gcur(const int* __restrict__ ofs_u,
                                                 const int* __restrict__ ofs_i,
                                                 int* __restrict__ gcur_s,
                                                 int* __restrict__ gcur_d) {
  int t = threadIdx.x;
  if (t < NBKT) {
    gcur_s[t] = ofs_u[t << 9];   // t<<9 <= 99840 < NU
    gcur_d[t] = ofs_i[t << 10];  // t<<10 <= 199680 < NI
  }
}

// ====== binA: per-block LDS counting sort of an edge chunk by node bucket, coalesced flush ======
__global__ __launch_bounds__(256) void binA_kernel(const int* __restrict__ key,
                                                   const int* __restrict__ oth,
                                                   int* __restrict__ gcur,
                                                   int2* __restrict__ temp, int shift) {
  __shared__ int2 stage[3907];
  __shared__ int lh[256], lpos[256], lstart[256], sc[256];
  const int tid = threadIdx.x;
  const int lo = (int)(((long long)NE * blockIdx.x) >> 8);
  const int hi = (int)(((long long)NE * (blockIdx.x + 1)) >> 8);
  lh[tid] = 0;
  __syncthreads();
  for (int e = lo + tid; e < hi; e += 256) atomicAdd(&lh[key[e] >> shift], 1);
  __syncthreads();
  int v = lh[tid];
  sc[tid] = v;
  __syncthreads();
  for (int off = 1; off < 256; off <<= 1) {
    int t = (tid >= off) ? sc[tid - off] : 0;
    __syncthreads();
    sc[tid] += t;
    __syncthreads();
  }
  lstart[tid] = sc[tid] - v;
  lpos[tid] = sc[tid] - v;
  __syncthreads();
  for (int e = lo + tid; e < hi; e += 256) {
    int k = key[e];
    int p = atomicAdd(&lpos[k >> shift], 1);
    stage[p] = make_int2(k, oth[e]);
  }
  __syncthreads();
  const int w = tid >> 6, lane = tid & 63;
  for (int b = w; b < 256; b += 4) {
    const int cnt = lh[b];
    if (cnt == 0) continue;
    int base = 0;
    if (lane == 0) base = atomicAdd(&gcur[b], cnt);
    base = __shfl(base, 0);
    const int s0 = lstart[b];
    for (int t = lane; t < cnt; t += 64) temp[base + t] = stage[s0 + t];
  }
}

// ====== placeB: per-bucket scatter into the bucket's contiguous CSR slice (XCD-local) ======
__global__ __launch_bounds__(256) void placeB_kernel(const int* __restrict__ ofs,
                                                     const int2* __restrict__ temp,
                                                     const int* __restrict__ cnt_other,
                                                     int* __restrict__ cur,
                                                     int2* __restrict__ by,
                                                     int shift, int n) {
  const int b = blockIdx.x;
  const int lo = ofs[min(b << shift, n)];
  const int hi = ofs[min((b + 1) << shift, n)];
  for (int k = lo + threadIdx.x; k < hi; k += 256) {
    const int2 t = temp[k];
    const float wgt = rsqrtf((float)cnt_other[t.y]);
    const int p = atomicAdd(&cur[t.x], 1);
    by[p] = make_int2(t.y, __builtin_bit_cast(int, wgt));
  }
}

// ================= f32 -> bf16 conversion (both feature arrays) =================
__global__ __launch_bounds__(256) void conv_kernel(const float* __restrict__ uf,
                                                   const float* __restrict__ itf,
                                                   unsigned short* __restrict__ hu,
                                                   unsigned short* __restrict__ hi) {
  int i = blockIdx.x * 256 + threadIdx.x;
  const int n4u = NU * 16;
  const float* in;
  unsigned short* outp;
  int j;
  if (i < n4u) {
    in = uf; outp = hu; j = i;
  } else if (i < n4u + NI * 16) {
    in = itf; outp = hi; j = i - n4u;
  } else return;
  float4 v = *(const float4*)&in[(size_t)j * 4];
  ushort4 o;
  o.x = (unsigned short)f2bf(v.x);
  o.y = (unsigned short)f2bf(v.y);
  o.z = (unsigned short)f2bf(v.z);
  o.w = (unsigned short)f2bf(v.w);
  *(ushort4*)&outp[(size_t)j * 4] = o;
}

// ================= g gather-sum (both directions, bf16 in/out) =================
__global__ __launch_bounds__(256) void gatherg_kernel(const int* __restrict__ ofs_i,
                                                      const int* __restrict__ ofs_u,
                                                      const int2* __restrict__ by_dst,
                                                      const int2* __restrict__ by_src,
                                                      const unsigned short* __restrict__ hu,
                                                      const unsigned short* __restrict__ hi,
                                                      unsigned short* __restrict__ g_i,
                                                      unsigned short* __restrict__ g_u,
                                                      float* __restrict__ c_i,
                                                      float* __restrict__ c_u) {
  const int lane = threadIdx.x & 63;
  const int w = threadIdx.x >> 6;
  const int j8 = lane & 7, grp = lane >> 3;
  const int r = blockIdx.x * 4 + w;
  if (r >= NI + NU) return;
  const bool item = r < NI;
  const int rr = item ? r : r - NI;
  const int* ofs = item ? ofs_i : ofs_u;
  const int2* pay = item ? by_dst : by_src;
  const unsigned short* hsrc = item ? hu : hi;
  unsigned short* g = item ? g_i : g_u;
  float* c = item ? c_i : c_u;

  const int lo = ofs[rr], hiE = ofs[rr + 1];
  float acc[8] = {0.f, 0.f, 0.f, 0.f, 0.f, 0.f, 0.f, 0.f};
  float cs = 0.f;
  for (int k = lo + grp; k < hiE; k += 8) {
    const int2 pw = pay[k];
    const float ww = __builtin_bit_cast(float, pw.y);
    const u16x8 hv = *(const u16x8*)(hsrc + (size_t)pw.x * 64 + j8 * 8);
#pragma unroll
    for (int j = 0; j < 8; ++j) acc[j] += ww * bf2f(hv[j]);
    cs += ww;
  }
#pragma unroll
  for (int m = 8; m < 64; m <<= 1) {
#pragma unroll
    for (int j = 0; j < 8; ++j) acc[j] += __shfl_xor(acc[j], m);
    cs += __shfl_xor(cs, m);
  }
  if (grp == 0) {
    const float rsn = (hiE > lo) ? rsqrtf((float)(hiE - lo)) : 0.f;
    u16x8 o;
#pragma unroll
    for (int j = 0; j < 8; ++j) o[j] = (unsigned short)f2bf(acc[j] * rsn);
    *(u16x8*)(g + (size_t)rr * 64 + j8 * 8) = o;
    if (j8 == 0) c[rr] = cs * rsn;
  }
}

// ========== node via MFMA (both directions): hnew = actnorm( g@W1 + (g.*hold)@W2 + c*(b1+b2) ) ==========
__global__ __launch_bounds__(256) void node_mfma_kernel(const unsigned short* __restrict__ g_i,
                                                        const unsigned short* __restrict__ g_u,
                                                        const float* __restrict__ c_i,
                                                        const float* __restrict__ c_u,
                                                        const unsigned short* __restrict__ hi,
                                                        const unsigned short* __restrict__ hu,
                                                        const float* __restrict__ W1,
                                                        const float* __restrict__ b1,
                                                        const float* __restrict__ W2,
                                                        const float* __restrict__ b2,
                                                        unsigned short* __restrict__ hi_new,
                                                        unsigned short* __restrict__ hu_new) {
  const int lane = threadIdx.x & 63;
  const int row16 = lane & 15;
  const int kgrp = lane >> 4;  // 0..3
  const int wid = (blockIdx.x * 256 + threadIdx.x) >> 6;
  const int nwaves = (gridDim.x * 256) >> 6;

  bf16x8 w1f[4][2], w2f[4][2];
#pragma unroll
  for (int nb = 0; nb < 4; ++nb)
#pragma unroll
    for (int kb = 0; kb < 2; ++kb) {
      const int n = nb * 16 + row16;
      const int k0 = kb * 32 + kgrp * 8;
      bf16x8 t1, t2;
#pragma unroll
      for (int j = 0; j < 8; ++j) {
        t1[j] = f2bf(W1[(k0 + j) * 64 + n]);
        t2[j] = f2bf(W2[(k0 + j) * 64 + n]);
      }
      w1f[nb][kb] = t1;
      w2f[nb][kb] = t2;
    }
  float bsum[4];
#pragma unroll
  for (int nb = 0; nb < 4; ++nb) bsum[nb] = b1[nb * 16 + row16] + b2[nb * 16 + row16];

  for (int t = wid; t < NTI + NTU; t += nwaves) {
    const bool item = t < NTI;
    const int tt = item ? t : t - NTI;
    const unsigned short* g = item ? g_i : g_u;
    const float* c = item ? c_i : c_u;
    const unsigned short* hold = item ? hi : hu;
    unsigned short* hnew = item ? hi_new : hu_new;
    const int r0 = tt * 16;

    const unsigned short* gp = g + (size_t)(r0 + row16) * 64 + kgrp * 8;
    const unsigned short* hp = hold + (size_t)(r0 + row16) * 64 + kgrp * 8;
    bf16x8 ag[2], ap[2];
#pragma unroll
    for (int kb = 0; kb < 2; ++kb) {
      const u16x8 gv = *(const u16x8*)(gp + kb * 32);
      const u16x8 hv = *(const u16x8*)(hp + kb * 32);
      ag[kb] = __builtin_bit_cast(bf16x8, gv);
      bf16x8 p;
#pragma unroll
      for (int j = 0; j < 8; ++j) p[j] = f2bf(bf2f(gv[j]) * bf2f(hv[j]));
      ap[kb] = p;
    }
    f32x4 acc[4];
#pragma unroll
    for (int nb = 0; nb < 4; ++nb) acc[nb] = (f32x4){0.f, 0.f, 0.f, 0.f};
#pragma unroll
    for (int nb = 0; nb < 4; ++nb)
#pragma unroll
      for (int kb = 0; kb < 2; ++kb) {
        acc[nb] = __builtin_amdgcn_mfma_f32_16x16x32_bf16(ag[kb], w1f[nb][kb], acc[nb], 0, 0, 0);
        acc[nb] = __builtin_amdgcn_mfma_f32_16x16x32_bf16(ap[kb], w2f[nb][kb], acc[nb], 0, 0, 0);
      }
    float cv[4];
#pragma unroll
    for (int reg = 0; reg < 4; ++reg) cv[reg] = c[r0 + kgrp * 4 + reg];
    float v[4][4];
    float ss[4] = {0.f, 0.f, 0.f, 0.f};
#pragma unroll
    for (int nb = 0; nb < 4; ++nb)
#pragma unroll
      for (int reg = 0; reg < 4; ++reg) {
        float x = acc[nb][reg] + cv[reg] * bsum[nb];
        x = (x > 0.f) ? x : 0.2f * x;
        v[nb][reg] = x;
        ss[reg] += x * x;
      }
#pragma unroll
    for (int m = 1; m < 16; m <<= 1)
#pragma unroll
      for (int reg = 0; reg < 4; ++reg) ss[reg] += __shfl_xor(ss[reg], m);
    float inv[4];
#pragma unroll
    for (int reg = 0; reg < 4; ++reg) inv[reg] = 1.0f / fmaxf(sqrtf(ss[reg]), 1e-12f);
#pragma unroll
    for (int reg = 0; reg < 4; ++reg) {
      const size_t rowbase = (size_t)(r0 + kgrp * 4 + reg) * 64;
#pragma unroll
      for (int nb = 0; nb < 4; ++nb)
        hnew[rowbase + nb * 16 + row16] = (unsigned short)f2bf(v[nb][reg] * inv[reg]);
    }
  }
}

// ================= output gathers =================
__global__ __launch_bounds__(256) void gather_f32_kernel(const float* __restrict__ hu,
                                                         const float* __restrict__ hi,
                                                         const int* __restrict__ users,
                                                         const int* __restrict__ pos,
                                                         const int* __restrict__ neg,
                                                         float* __restrict__ out) {
  int t = blockIdx.x * 256 + threadIdx.x;
  if (t >= 3 * NB * 64) return;
  int j = t & 63;
  int b = (t >> 6) & (NB - 1);
  int which = t / (NB * 64);
  int row = (which == 0) ? users[b] : ((which == 1) ? pos[b] : neg[b]);
  const float* h = (which == 0) ? hu : hi;
  out[(size_t)which * NB * 256 + (size_t)b * 256 + j] = h[(size_t)row * 64 + j];
}

__global__ __launch_bounds__(256) void gather_bf_kernel(const unsigned short* __restrict__ hu,
                                                        const unsigned short* __restrict__ hi,
                                                        const int* __restrict__ users,
                                                        const int* __restrict__ pos,
                                                        const int* __restrict__ neg,
                                                        float* __restrict__ out, int stage) {
  int t = blockIdx.x * 256 + threadIdx.x;
  if (t >= 3 * NB * 64) return;
  int j = t & 63;
  int b = (t >> 6) & (NB - 1);
  int which = t / (NB * 64);
  int row = (which == 0) ? users[b] : ((which == 1) ? pos[b] : neg[b]);
  const unsigned short* h = (which == 0) ? hu : hi;
  out[(size_t)which * NB * 256 + (size_t)b * 256 + (size_t)stage * 64 + j] =
      bf2f(h[(size_t)row * 64 + j]);
}

extern "C" void kernel_launch(void* const* d_in, const int* in_sizes, int n_in,
                              void* d_out, int out_size, void* d_ws, size_t ws_size,
                              hipStream_t stream) {
  (void)in_sizes; (void)n_in; (void)out_size; (void)ws_size;
  const float* user_feat = (const float*)d_in[0];
  const float* item_feat = (const float*)d_in[1];
  const float* W1 = (const float*)d_in[2];
  const float* b1 = (const float*)d_in[3];
  const float* W2 = (const float*)d_in[4];
  const float* b2 = (const float*)d_in[5];
  const int* edge_src = (const int*)d_in[6];
  const int* edge_dst = (const int*)d_in[7];
  const int* users = (const int*)d_in[8];
  const int* pos_items = (const int*)d_in[9];
  const int* neg_items = (const int*)d_in[10];
  float* out = (float*)d_out;

  char* base = (char*)d_ws;
  size_t ofsz = 0;
  auto alloc = [&](size_t bytes) -> char* {
    char* r = base + ofsz;
    ofsz += (bytes + 1023) & ~(size_t)1023;
    return r;
  };
  int* ofs_u = (int*)alloc((NU + 1) * 4);
  int* ofs_i = (int*)alloc((NI + 1) * 4);
  int* cnt_u = (int*)alloc((size_t)NU * 4);
  int* cnt_i = (int*)alloc((size_t)NI * 4);
  int* cur_u = (int*)alloc((size_t)NU * 4);
  int* cur_i = (int*)alloc((size_t)NI * 4);
  int* gcur_s = (int*)alloc(256 * 4);
  int* gcur_d = (int*)alloc(256 * 4);
  int* partials = (int*)alloc(4096);
  int2* by_src = (int2*)alloc((size_t)NE * 8);
  int2* by_dst = (int2*)alloc((size_t)NE * 8);
  int2* temp_s = (int2*)alloc((size_t)NE * 8);
  int2* temp_d = (int2*)alloc((size_t)NE * 8);
  float* c_u = (float*)alloc((size_t)NU * 4);
  float* c_i = (float*)alloc((size_t)NI * 4);
  unsigned short* g_u = (unsigned short*)alloc((size_t)NU * 64 * 2);
  unsigned short* g_i = (unsigned short*)alloc((size_t)NI * 64 * 2);
  unsigned short* hbU0 = (unsigned short*)alloc((size_t)NU * 64 * 2);
  unsigned short* hbU1 = (unsigned short*)alloc((size_t)NU * 64 * 2);
  unsigned short* hbI0 = (unsigned short*)alloc((size_t)NI * 64 * 2);
  unsigned short* hbI1 = (unsigned short*)alloc((size_t)NI * 64 * 2);

  unsigned short* bufU[2] = {hbU1, hbU0};
  unsigned short* bufI[2] = {hbI1, hbI0};

  hipMemsetAsync(cnt_u, 0, (size_t)NU * 4, stream);
  hipMemsetAsync(cnt_i, 0, (size_t)NI * 4, stream);
  hist_kernel<<<(NE + 255) / 256, 256, 0, stream>>>(edge_src, edge_dst, cnt_u, cnt_i);

  const int nbU = (NU + 255) / 256, nbI = (NI + 255) / 256;
  scan_blocks<<<nbU, 256, 0, stream>>>(cnt_u, ofs_u, partials, NU);
  scan_partials<<<1, 1024, 0, stream>>>(partials, nbU);
  add_offsets<<<nbU, 256, 0, stream>>>(ofs_u, partials, NU, NE);
  scan_blocks<<<nbI, 256, 0, stream>>>(cnt_i, ofs_i, partials, NI);
  scan_partials<<<1, 1024, 0, stream>>>(partials, nbI);
  add_offsets<<<nbI, 256, 0, stream>>>(ofs_i, partials, NI, NE);

  copy_int<<<nbU, 256, 0, stream>>>(ofs_u, cur_u, NU);
  copy_int<<<nbI, 256, 0, stream>>>(ofs_i, cur_i, NI);
  init_gcur<<<1, 256, 0, stream>>>(ofs_u, ofs_i, gcur_s, gcur_d);

  binA_kernel<<<256, 256, 0, stream>>>(edge_src, edge_dst, gcur_s, temp_s, 9);
  binA_kernel<<<256, 256, 0, stream>>>(edge_dst, edge_src, gcur_d, temp_d, 10);
  placeB_kernel<<<NBKT, 256, 0, stream>>>(ofs_u, temp_s, cnt_i, cur_u, by_src, 9, NU);
  placeB_kernel<<<NBKT, 256, 0, stream>>>(ofs_i, temp_d, cnt_u, cur_i, by_dst, 10, NI);

  conv_kernel<<<((NU + NI) * 16 + 255) / 256, 256, 0, stream>>>(user_feat, item_feat, hbU0, hbI0);

  gather_f32_kernel<<<(3 * NB * 64 + 255) / 256, 256, 0, stream>>>(
      user_feat, item_feat, users, pos_items, neg_items, out);

  const unsigned short* hu = hbU0;
  const unsigned short* hi = hbI0;
  for (int l = 0; l < 3; ++l) {
    unsigned short* hu_new = bufU[l & 1];
    unsigned short* hi_new = bufI[l & 1];
    gatherg_kernel<<<(NI + NU + 3) / 4, 256, 0, stream>>>(ofs_i, ofs_u, by_dst, by_src,
                                                          hu, hi, g_i, g_u, c_i, c_u);
    node_mfma_kernel<<<1024, 256, 0, stream>>>(g_i, g_u, c_i, c_u, hi, hu,
                                               W1 + l * 4096, b1 + l * 64,
                                               W2 + l * 4096, b2 + l * 64, hi_new, hu_new);
    gather_bf_kernel<<<(3 * NB * 64 + 255) / 256, 256, 0, stream>>>(
        hu_new, hi_new, users, pos_items, neg_items, out, l + 1);
    hu = hu_new;
    hi = hi_new;
  }
}

// Round 6
// 505.424 us; speedup vs baseline: 2.1407x; 2.1407x over previous
//
#include <hip/hip_runtime.h>

#define NU 100000
#define NI 200000
#define NE 1000000
#define NB 4096
#define CAP 16384
#define NBS 98   // src buckets: ceil(100000/1024), shift 10
#define NBD 98   // dst buckets: ceil(200000/2048), shift 11
#define NTI (NI / 16)
#define NTU (NU / 16)

typedef __attribute__((ext_vector_type(8))) short bf16x8;
typedef __attribute__((ext_vector_type(4))) float f32x4;
typedef __attribute__((ext_vector_type(8))) unsigned short u16x8;

static __device__ __forceinline__ short f2bf(float f) {
  unsigned u = __builtin_bit_cast(unsigned, f);
  unsigned r = (u + 0x7fffu + ((u >> 16) & 1u)) >> 16;
  return (short)r;
}
static __device__ __forceinline__ float bf2f(unsigned short u) {
  return __builtin_bit_cast(float, ((unsigned)u) << 16);
}

// ====== binA v2: per-block LDS histogram + run reservation + direct scatter to bucket arena ======
// grid: 1024 blocks; blocks [0,512) bin by src (shift 10), [512,1024) by dst (shift 11).
__global__ __launch_bounds__(256) void binA_kernel(const int* __restrict__ src,
                                                   const int* __restrict__ dst,
                                                   int* __restrict__ gcur_s,
                                                   int* __restrict__ gcur_d,
                                                   int2* __restrict__ temp_s,
                                                   int2* __restrict__ temp_d) {
  __shared__ int lh[128], lbase[128], lpos[128];
  const int dir = blockIdx.x >> 9;          // 0 = src, 1 = dst
  const int cb = blockIdx.x & 511;
  const int lo = (int)(((long long)NE * cb) >> 9);
  const int hi = (int)(((long long)NE * (cb + 1)) >> 9);
  const int* key = dir ? dst : src;
  const int* oth = dir ? src : dst;
  int* gcur = dir ? gcur_d : gcur_s;
  int2* temp = dir ? temp_d : temp_s;
  const int shift = dir ? 11 : 10;
  const int tid = threadIdx.x;
  if (tid < 128) lh[tid] = 0;
  __syncthreads();
  for (int e = lo + tid; e < hi; e += 256) atomicAdd(&lh[key[e] >> shift], 1);
  __syncthreads();
  if (tid < 128) {
    const int c = lh[tid];
    lbase[tid] = c ? atomicAdd(&gcur[tid], c) : 0;
    lpos[tid] = 0;
  }
  __syncthreads();
  for (int e = lo + tid; e < hi; e += 256) {
    const int k = key[e];
    const int b = k >> shift;
    const int p = lbase[b] + atomicAdd(&lpos[b], 1);
    temp[(size_t)b * CAP + p] = make_int2(k, oth[e]);
  }
}

// ====== tiny serial scan of bucket totals ======
__global__ void bktscan_kernel(const int* __restrict__ gcur_s, const int* __restrict__ gcur_d,
                               int* __restrict__ bktofs_s, int* __restrict__ bktofs_d,
                               int* __restrict__ ofs_u, int* __restrict__ ofs_i) {
  const int t = threadIdx.x;
  if (t == 0) {
    int a = 0;
    for (int i = 0; i < NBS; ++i) { bktofs_s[i] = a; a += gcur_s[i]; }
    bktofs_s[NBS] = a;
    ofs_u[NU] = NE;
  }
  if (t == 1) {
    int a = 0;
    for (int i = 0; i < NBD; ++i) { bktofs_d[i] = a; a += gcur_d[i]; }
    bktofs_d[NBD] = a;
    ofs_i[NI] = NE;
  }
}

// ====== placeB v2: per-bucket LDS counting sort -> ofs, rs, CSR payload (nbr only, 4B) ======
// grid: NBS + NBD blocks. All node-level cursors live in LDS; global writes are
// sequential (ofs, rs) or confined to the bucket's contiguous CSR slice (by).
__global__ __launch_bounds__(256) void placeB_kernel(const int2* __restrict__ temp_s,
                                                     const int2* __restrict__ temp_d,
                                                     const int* __restrict__ gcur_s,
                                                     const int* __restrict__ gcur_d,
                                                     const int* __restrict__ bktofs_s,
                                                     const int* __restrict__ bktofs_d,
                                                     int* __restrict__ ofs_u, int* __restrict__ ofs_i,
                                                     float* __restrict__ rs_u, float* __restrict__ rs_i,
                                                     int* __restrict__ by_src, int* __restrict__ by_dst) {
  __shared__ int cnt[2048];
  __shared__ int exc[2048];
  __shared__ int wsum[256];
  const bool isdst = blockIdx.x >= NBS;
  const int b = isdst ? (int)blockIdx.x - NBS : (int)blockIdx.x;
  const int shift = isdst ? 11 : 10;
  const int nodelo = b << shift;
  const int n = isdst ? NI : NU;
  const int2* temp = (isdst ? temp_d : temp_s) + (size_t)b * CAP;
  const int ecnt = (isdst ? gcur_d : gcur_s)[b];
  const int bbase = (isdst ? bktofs_d : bktofs_s)[b];
  int* ofs = isdst ? ofs_i : ofs_u;
  float* rs = isdst ? rs_i : rs_u;
  int* by = isdst ? by_dst : by_src;
  const int tid = threadIdx.x;
  const int NN = 1 << shift;  // 1024 or 2048

  for (int j = tid; j < NN; j += 256) cnt[j] = 0;
  __syncthreads();
  for (int k = tid; k < ecnt; k += 256) atomicAdd(&cnt[temp[k].x - nodelo], 1);
  __syncthreads();
  // blocked exclusive scan of cnt[0..NN)
  const int per = NN >> 8;  // 4 or 8
  int s = 0;
  for (int j = 0; j < per; ++j) s += cnt[tid * per + j];
  wsum[tid] = s;
  __syncthreads();
  for (int off = 1; off < 256; off <<= 1) {
    int t2 = (tid >= off) ? wsum[tid - off] : 0;
    __syncthreads();
    wsum[tid] += t2;
    __syncthreads();
  }
  int run = wsum[tid] - s;
  for (int j = 0; j < per; ++j) {
    const int idx = tid * per + j;
    exc[idx] = run;
    run += cnt[idx];
  }
  __syncthreads();
  // sequential ofs / rs writes
  for (int j = tid; j < NN; j += 256) {
    const int node = nodelo + j;
    if (node < n) {
      ofs[node] = bbase + exc[j];
      const int d = cnt[j];
      rs[node] = d > 0 ? rsqrtf((float)d) : 0.f;
    }
  }
  __syncthreads();
  for (int j = tid; j < NN; j += 256) cnt[j] = exc[j];  // cnt becomes cursor
  __syncthreads();
  for (int k = tid; k < ecnt; k += 256) {
    const int2 t2 = temp[k];
    const int p = bbase + atomicAdd(&cnt[t2.x - nodelo], 1);
    by[p] = t2.y;
  }
}

// ================= f32 -> bf16 conversion (both feature arrays) =================
__global__ __launch_bounds__(256) void conv_kernel(const float* __restrict__ uf,
                                                   const float* __restrict__ itf,
                                                   unsigned short* __restrict__ hu,
                                                   unsigned short* __restrict__ hi) {
  int i = blockIdx.x * 256 + threadIdx.x;
  const int n4u = NU * 16;
  const float* in;
  unsigned short* outp;
  int j;
  if (i < n4u) {
    in = uf; outp = hu; j = i;
  } else if (i < n4u + NI * 16) {
    in = itf; outp = hi; j = i - n4u;
  } else return;
  float4 v = *(const float4*)&in[(size_t)j * 4];
  ushort4 o;
  o.x = (unsigned short)f2bf(v.x);
  o.y = (unsigned short)f2bf(v.y);
  o.z = (unsigned short)f2bf(v.z);
  o.w = (unsigned short)f2bf(v.w);
  *(ushort4*)&outp[(size_t)j * 4] = o;
}

// ================= g gather-sum (both directions, bf16 in/out) =================
__global__ __launch_bounds__(256) void gatherg_kernel(const int* __restrict__ ofs_i,
                                                      const int* __restrict__ ofs_u,
                                                      const int* __restrict__ by_dst,
                                                      const int* __restrict__ by_src,
                                                      const float* __restrict__ rs_u,
                                                      const float* __restrict__ rs_i,
                                                      const unsigned short* __restrict__ hu,
                                                      const unsigned short* __restrict__ hi,
                                                      unsigned short* __restrict__ g_i,
                                                      unsigned short* __restrict__ g_u,
                                                      float* __restrict__ c_i,
                                                      float* __restrict__ c_u) {
  const int lane = threadIdx.x & 63;
  const int w = threadIdx.x >> 6;
  const int j8 = lane & 7, grp = lane >> 3;
  const int r = blockIdx.x * 4 + w;
  if (r >= NI + NU) return;
  const bool item = r < NI;
  const int rr = item ? r : r - NI;
  const int* ofs = item ? ofs_i : ofs_u;
  const int* pay = item ? by_dst : by_src;
  const float* rso = item ? rs_u : rs_i;   // weight of the neighbor
  const float* rsw = item ? rs_i : rs_u;   // own scale
  const unsigned short* hsrc = item ? hu : hi;
  unsigned short* g = item ? g_i : g_u;
  float* c = item ? c_i : c_u;

  const int lo = ofs[rr], hiE = ofs[rr + 1];
  float acc[8] = {0.f, 0.f, 0.f, 0.f, 0.f, 0.f, 0.f, 0.f};
  float cs = 0.f;
  for (int k = lo + grp; k < hiE; k += 8) {
    const int nb = pay[k];
    const float ww = rso[nb];
    const u16x8 hv = *(const u16x8*)(hsrc + (size_t)nb * 64 + j8 * 8);
#pragma unroll
    for (int j = 0; j < 8; ++j) acc[j] += ww * bf2f(hv[j]);
    cs += ww;
  }
#pragma unroll
  for (int m = 8; m < 64; m <<= 1) {
#pragma unroll
    for (int j = 0; j < 8; ++j) acc[j] += __shfl_xor(acc[j], m);
    cs += __shfl_xor(cs, m);
  }
  if (grp == 0) {
    const float rsn = rsw[rr];
    u16x8 o;
#pragma unroll
    for (int j = 0; j < 8; ++j) o[j] = (unsigned short)f2bf(acc[j] * rsn);
    *(u16x8*)(g + (size_t)rr * 64 + j8 * 8) = o;
    if (j8 == 0) c[rr] = cs * rsn;
  }
}

// ========== node via MFMA (both directions): hnew = actnorm( g@W1 + (g.*hold)@W2 + c*(b1+b2) ) ==========
__global__ __launch_bounds__(256) void node_mfma_kernel(const unsigned short* __restrict__ g_i,
                                                        const unsigned short* __restrict__ g_u,
                                                        const float* __restrict__ c_i,
                                                        const float* __restrict__ c_u,
                                                        const unsigned short* __restrict__ hi,
                                                        const unsigned short* __restrict__ hu,
                                                        const float* __restrict__ W1,
                                                        const float* __restrict__ b1,
                                                        const float* __restrict__ W2,
                                                        const float* __restrict__ b2,
                                                        unsigned short* __restrict__ hi_new,
                                                        unsigned short* __restrict__ hu_new) {
  const int lane = threadIdx.x & 63;
  const int row16 = lane & 15;
  const int kgrp = lane >> 4;  // 0..3
  const int wid = (blockIdx.x * 256 + threadIdx.x) >> 6;
  const int nwaves = (gridDim.x * 256) >> 6;

  bf16x8 w1f[4][2], w2f[4][2];
#pragma unroll
  for (int nb = 0; nb < 4; ++nb)
#pragma unroll
    for (int kb = 0; kb < 2; ++kb) {
      const int n = nb * 16 + row16;
      const int k0 = kb * 32 + kgrp * 8;
      bf16x8 t1, t2;
#pragma unroll
      for (int j = 0; j < 8; ++j) {
        t1[j] = f2bf(W1[(k0 + j) * 64 + n]);
        t2[j] = f2bf(W2[(k0 + j) * 64 + n]);
      }
      w1f[nb][kb] = t1;
      w2f[nb][kb] = t2;
    }
  float bsum[4];
#pragma unroll
  for (int nb = 0; nb < 4; ++nb) bsum[nb] = b1[nb * 16 + row16] + b2[nb * 16 + row16];

  for (int t = wid; t < NTI + NTU; t += nwaves) {
    const bool item = t < NTI;
    const int tt = item ? t : t - NTI;
    const unsigned short* g = item ? g_i : g_u;
    const float* c = item ? c_i : c_u;
    const unsigned short* hold = item ? hi : hu;
    unsigned short* hnew = item ? hi_new : hu_new;
    const int r0 = tt * 16;

    const unsigned short* gp = g + (size_t)(r0 + row16) * 64 + kgrp * 8;
    const unsigned short* hp = hold + (size_t)(r0 + row16) * 64 + kgrp * 8;
    bf16x8 ag[2], ap[2];
#pragma unroll
    for (int kb = 0; kb < 2; ++kb) {
      const u16x8 gv = *(const u16x8*)(gp + kb * 32);
      const u16x8 hv = *(const u16x8*)(hp + kb * 32);
      ag[kb] = __builtin_bit_cast(bf16x8, gv);
      bf16x8 p;
#pragma unroll
      for (int j = 0; j < 8; ++j) p[j] = f2bf(bf2f(gv[j]) * bf2f(hv[j]));
      ap[kb] = p;
    }
    f32x4 acc[4];
#pragma unroll
    for (int nb = 0; nb < 4; ++nb) acc[nb] = (f32x4){0.f, 0.f, 0.f, 0.f};
#pragma unroll
    for (int nb = 0; nb < 4; ++nb)
#pragma unroll
      for (int kb = 0; kb < 2; ++kb) {
        acc[nb] = __builtin_amdgcn_mfma_f32_16x16x32_bf16(ag[kb], w1f[nb][kb], acc[nb], 0, 0, 0);
        acc[nb] = __builtin_amdgcn_mfma_f32_16x16x32_bf16(ap[kb], w2f[nb][kb], acc[nb], 0, 0, 0);
      }
    float cv[4];
#pragma unroll
    for (int reg = 0; reg < 4; ++reg) cv[reg] = c[r0 + kgrp * 4 + reg];
    float v[4][4];
    float ss[4] = {0.f, 0.f, 0.f, 0.f};
#pragma unroll
    for (int nb = 0; nb < 4; ++nb)
#pragma unroll
      for (int reg = 0; reg < 4; ++reg) {
        float x = acc[nb][reg] + cv[reg] * bsum[nb];
        x = (x > 0.f) ? x : 0.2f * x;
        v[nb][reg] = x;
        ss[reg] += x * x;
      }
#pragma unroll
    for (int m = 1; m < 16; m <<= 1)
#pragma unroll
      for (int reg = 0; reg < 4; ++reg) ss[reg] += __shfl_xor(ss[reg], m);
    float inv[4];
#pragma unroll
    for (int reg = 0; reg < 4; ++reg) inv[reg] = 1.0f / fmaxf(sqrtf(ss[reg]), 1e-12f);
#pragma unroll
    for (int reg = 0; reg < 4; ++reg) {
      const size_t rowbase = (size_t)(r0 + kgrp * 4 + reg) * 64;
#pragma unroll
      for (int nb = 0; nb < 4; ++nb)
        hnew[rowbase + nb * 16 + row16] = (unsigned short)f2bf(v[nb][reg] * inv[reg]);
    }
  }
}

// ================= output gathers =================
__global__ __launch_bounds__(256) void gather_f32_kernel(const float* __restrict__ hu,
                                                         const float* __restrict__ hi,
                                                         const int* __restrict__ users,
                                                         const int* __restrict__ pos,
                                                         const int* __restrict__ neg,
                                                         float* __restrict__ out) {
  int t = blockIdx.x * 256 + threadIdx.x;
  if (t >= 3 * NB * 64) return;
  int j = t & 63;
  int b = (t >> 6) & (NB - 1);
  int which = t / (NB * 64);
  int row = (which == 0) ? users[b] : ((which == 1) ? pos[b] : neg[b]);
  const float* h = (which == 0) ? hu : hi;
  out[(size_t)which * NB * 256 + (size_t)b * 256 + j] = h[(size_t)row * 64 + j];
}

__global__ __launch_bounds__(256) void gather_bf_kernel(const unsigned short* __restrict__ hu,
                                                        const unsigned short* __restrict__ hi,
                                                        const int* __restrict__ users,
                                                        const int* __restrict__ pos,
                                                        const int* __restrict__ neg,
                                                        float* __restrict__ out, int stage) {
  int t = blockIdx.x * 256 + threadIdx.x;
  if (t >= 3 * NB * 64) return;
  int j = t & 63;
  int b = (t >> 6) & (NB - 1);
  int which = t / (NB * 64);
  int row = (which == 0) ? users[b] : ((which == 1) ? pos[b] : neg[b]);
  const unsigned short* h = (which == 0) ? hu : hi;
  out[(size_t)which * NB * 256 + (size_t)b * 256 + (size_t)stage * 64 + j] =
      bf2f(h[(size_t)row * 64 + j]);
}

extern "C" void kernel_launch(void* const* d_in, const int* in_sizes, int n_in,
                              void* d_out, int out_size, void* d_ws, size_t ws_size,
                              hipStream_t stream) {
  (void)in_sizes; (void)n_in; (void)out_size; (void)ws_size;
  const float* user_feat = (const float*)d_in[0];
  const float* item_feat = (const float*)d_in[1];
  const float* W1 = (const float*)d_in[2];
  const float* b1 = (const float*)d_in[3];
  const float* W2 = (const float*)d_in[4];
  const float* b2 = (const float*)d_in[5];
  const int* edge_src = (const int*)d_in[6];
  const int* edge_dst = (const int*)d_in[7];
  const int* users = (const int*)d_in[8];
  const int* pos_items = (const int*)d_in[9];
  const int* neg_items = (const int*)d_in[10];
  float* out = (float*)d_out;

  char* base = (char*)d_ws;
  size_t ofsz = 0;
  auto alloc = [&](size_t bytes) -> char* {
    char* r = base + ofsz;
    ofsz += (bytes + 1023) & ~(size_t)1023;
    return r;
  };
  int* ofs_u = (int*)alloc((NU + 1) * 4);
  int* ofs_i = (int*)alloc((NI + 1) * 4);
  int* gcur_s = (int*)alloc(128 * 4);
  int* gcur_d = (int*)alloc(128 * 4);
  int* bktofs_s = (int*)alloc(128 * 4);
  int* bktofs_d = (int*)alloc(128 * 4);
  int2* temp_s = (int2*)alloc((size_t)NBS * CAP * 8);
  int2* temp_d = (int2*)alloc((size_t)NBD * CAP * 8);
  int* by_src = (int*)alloc((size_t)NE * 4);
  int* by_dst = (int*)alloc((size_t)NE * 4);
  float* rs_u = (float*)alloc((size_t)NU * 4);
  float* rs_i = (float*)alloc((size_t)NI * 4);
  float* c_u = (float*)alloc((size_t)NU * 4);
  float* c_i = (float*)alloc((size_t)NI * 4);
  unsigned short* g_u = (unsigned short*)alloc((size_t)NU * 64 * 2);
  unsigned short* g_i = (unsigned short*)alloc((size_t)NI * 64 * 2);
  unsigned short* hbU0 = (unsigned short*)alloc((size_t)NU * 64 * 2);
  unsigned short* hbU1 = (unsigned short*)alloc((size_t)NU * 64 * 2);
  unsigned short* hbI0 = (unsigned short*)alloc((size_t)NI * 64 * 2);
  unsigned short* hbI1 = (unsigned short*)alloc((size_t)NI * 64 * 2);

  unsigned short* bufU[2] = {hbU1, hbU0};
  unsigned short* bufI[2] = {hbI1, hbI0};

  hipMemsetAsync(gcur_s, 0, 128 * 4, stream);
  hipMemsetAsync(gcur_d, 0, 128 * 4, stream);
  binA_kernel<<<1024, 256, 0, stream>>>(edge_src, edge_dst, gcur_s, gcur_d, temp_s, temp_d);
  bktscan_kernel<<<1, 64, 0, stream>>>(gcur_s, gcur_d, bktofs_s, bktofs_d, ofs_u, ofs_i);
  placeB_kernel<<<NBS + NBD, 256, 0, stream>>>(temp_s, temp_d, gcur_s, gcur_d,
                                               bktofs_s, bktofs_d, ofs_u, ofs_i,
                                               rs_u, rs_i, by_src, by_dst);

  conv_kernel<<<((NU + NI) * 16 + 255) / 256, 256, 0, stream>>>(user_feat, item_feat, hbU0, hbI0);

  gather_f32_kernel<<<(3 * NB * 64 + 255) / 256, 256, 0, stream>>>(
      user_feat, item_feat, users, pos_items, neg_items, out);

  const unsigned short* hu = hbU0;
  const unsigned short* hi = hbI0;
  for (int l = 0; l < 3; ++l) {
    unsigned short* hu_new = bufU[l & 1];
    unsigned short* hi_new = bufI[l & 1];
    gatherg_kernel<<<(NI + NU + 3) / 4, 256, 0, stream>>>(ofs_i, ofs_u, by_dst, by_src,
                                                          rs_u, rs_i, hu, hi, g_i, g_u, c_i, c_u);
    node_mfma_kernel<<<1024, 256, 0, stream>>>(g_i, g_u, c_i, c_u, hi, hu,
                                               W1 + l * 4096, b1 + l * 64,
                                               W2 + l * 4096, b2 + l * 64, hi_new, hu_new);
    gather_bf_kernel<<<(3 * NB * 64 + 255) / 256, 256, 0, stream>>>(
        hu_new, hi_new, users, pos_items, neg_items, out, l + 1);
    hu = hu_new;
    hi = hi_new;
  }
}

// Round 7
// 426.950 us; speedup vs baseline: 2.5342x; 1.1838x over previous
//
#include <hip/hip_runtime.h>

#define NU 100000
#define NI 200000
#define NE 1000000
#define NB 4096
#define CAP 16384
#define NBS 98   // src buckets: ceil(100000/1024), shift 10
#define NBD 98   // dst buckets: ceil(200000/2048), shift 11
#define NTI (NI / 16)
#define NTU (NU / 16)

typedef __attribute__((ext_vector_type(8))) short bf16x8;
typedef __attribute__((ext_vector_type(4))) float f32x4;
typedef __attribute__((ext_vector_type(8))) unsigned short u16x8;

static __device__ __forceinline__ short f2bf(float f) {
  unsigned u = __builtin_bit_cast(unsigned, f);
  unsigned r = (u + 0x7fffu + ((u >> 16) & 1u)) >> 16;
  return (short)r;
}
static __device__ __forceinline__ float bf2f(unsigned short u) {
  return __builtin_bit_cast(float, ((unsigned)u) << 16);
}

// ====== binA: per-block LDS histogram + run reservation + direct scatter to bucket arena ======
__global__ __launch_bounds__(256) void binA_kernel(const int* __restrict__ src,
                                                   const int* __restrict__ dst,
                                                   int* __restrict__ gcur_s,
                                                   int* __restrict__ gcur_d,
                                                   int2* __restrict__ temp_s,
                                                   int2* __restrict__ temp_d) {
  __shared__ int lh[128], lbase[128], lpos[128];
  const int dir = blockIdx.x >> 9;          // 0 = src, 1 = dst
  const int cb = blockIdx.x & 511;
  const int lo = (int)(((long long)NE * cb) >> 9);
  const int hi = (int)(((long long)NE * (cb + 1)) >> 9);
  const int* key = dir ? dst : src;
  const int* oth = dir ? src : dst;
  int* gcur = dir ? gcur_d : gcur_s;
  int2* temp = dir ? temp_d : temp_s;
  const int shift = dir ? 11 : 10;
  const int tid = threadIdx.x;
  if (tid < 128) lh[tid] = 0;
  __syncthreads();
  for (int e = lo + tid; e < hi; e += 256) atomicAdd(&lh[key[e] >> shift], 1);
  __syncthreads();
  if (tid < 128) {
    const int c = lh[tid];
    lbase[tid] = c ? atomicAdd(&gcur[tid], c) : 0;
    lpos[tid] = 0;
  }
  __syncthreads();
  for (int e = lo + tid; e < hi; e += 256) {
    const int k = key[e];
    const int b = k >> shift;
    const int p = lbase[b] + atomicAdd(&lpos[b], 1);
    temp[(size_t)b * CAP + p] = make_int2(k, oth[e]);
  }
}

// ====== tiny serial scan of bucket totals ======
__global__ void bktscan_kernel(const int* __restrict__ gcur_s, const int* __restrict__ gcur_d,
                               int* __restrict__ bktofs_s, int* __restrict__ bktofs_d,
                               int* __restrict__ ofs_u, int* __restrict__ ofs_i) {
  const int t = threadIdx.x;
  if (t == 0) {
    int a = 0;
    for (int i = 0; i < NBS; ++i) { bktofs_s[i] = a; a += gcur_s[i]; }
    bktofs_s[NBS] = a;
    ofs_u[NU] = NE;
  }
  if (t == 1) {
    int a = 0;
    for (int i = 0; i < NBD; ++i) { bktofs_d[i] = a; a += gcur_d[i]; }
    bktofs_d[NBD] = a;
    ofs_i[NI] = NE;
  }
}

// ====== placeB: per-bucket LDS counting sort -> ofs, rs, CSR payload (nbr only, 4B) ======
__global__ __launch_bounds__(256) void placeB_kernel(const int2* __restrict__ temp_s,
                                                     const int2* __restrict__ temp_d,
                                                     const int* __restrict__ gcur_s,
                                                     const int* __restrict__ gcur_d,
                                                     const int* __restrict__ bktofs_s,
                                                     const int* __restrict__ bktofs_d,
                                                     int* __restrict__ ofs_u, int* __restrict__ ofs_i,
                                                     float* __restrict__ rs_u, float* __restrict__ rs_i,
                                                     int* __restrict__ by_src, int* __restrict__ by_dst) {
  __shared__ int cnt[2048];
  __shared__ int exc[2048];
  __shared__ int wsum[256];
  const bool isdst = blockIdx.x >= NBS;
  const int b = isdst ? (int)blockIdx.x - NBS : (int)blockIdx.x;
  const int shift = isdst ? 11 : 10;
  const int nodelo = b << shift;
  const int n = isdst ? NI : NU;
  const int2* temp = (isdst ? temp_d : temp_s) + (size_t)b * CAP;
  const int ecnt = (isdst ? gcur_d : gcur_s)[b];
  const int bbase = (isdst ? bktofs_d : bktofs_s)[b];
  int* ofs = isdst ? ofs_i : ofs_u;
  float* rs = isdst ? rs_i : rs_u;
  int* by = isdst ? by_dst : by_src;
  const int tid = threadIdx.x;
  const int NN = 1 << shift;  // 1024 or 2048

  for (int j = tid; j < NN; j += 256) cnt[j] = 0;
  __syncthreads();
  for (int k = tid; k < ecnt; k += 256) atomicAdd(&cnt[temp[k].x - nodelo], 1);
  __syncthreads();
  const int per = NN >> 8;  // 4 or 8
  int s = 0;
  for (int j = 0; j < per; ++j) s += cnt[tid * per + j];
  wsum[tid] = s;
  __syncthreads();
  for (int off = 1; off < 256; off <<= 1) {
    int t2 = (tid >= off) ? wsum[tid - off] : 0;
    __syncthreads();
    wsum[tid] += t2;
    __syncthreads();
  }
  int run = wsum[tid] - s;
  for (int j = 0; j < per; ++j) {
    const int idx = tid * per + j;
    exc[idx] = run;
    run += cnt[idx];
  }
  __syncthreads();
  for (int j = tid; j < NN; j += 256) {
    const int node = nodelo + j;
    if (node < n) {
      ofs[node] = bbase + exc[j];
      const int d = cnt[j];
      rs[node] = d > 0 ? rsqrtf((float)d) : 0.f;
    }
  }
  __syncthreads();
  for (int j = tid; j < NN; j += 256) cnt[j] = exc[j];  // cnt becomes cursor
  __syncthreads();
  for (int k = tid; k < ecnt; k += 256) {
    const int2 t2 = temp[k];
    const int p = bbase + atomicAdd(&cnt[t2.x - nodelo], 1);
    by[p] = t2.y;
  }
}

// ================= f32 -> bf16 conversion (both feature arrays) =================
__global__ __launch_bounds__(256) void conv_kernel(const float* __restrict__ uf,
                                                   const float* __restrict__ itf,
                                                   unsigned short* __restrict__ hu,
                                                   unsigned short* __restrict__ hi) {
  int i = blockIdx.x * 256 + threadIdx.x;
  const int n4u = NU * 16;
  const float* in;
  unsigned short* outp;
  int j;
  if (i < n4u) {
    in = uf; outp = hu; j = i;
  } else if (i < n4u + NI * 16) {
    in = itf; outp = hi; j = i - n4u;
  } else return;
  float4 v = *(const float4*)&in[(size_t)j * 4];
  ushort4 o;
  o.x = (unsigned short)f2bf(v.x);
  o.y = (unsigned short)f2bf(v.y);
  o.z = (unsigned short)f2bf(v.z);
  o.w = (unsigned short)f2bf(v.w);
  *(ushort4*)&outp[(size_t)j * 4] = o;
}

// ========== fused layer: gather + (g@W1 + (g.*hold)@W2 + c*b) + leakyReLU + L2norm ==========
// One wave per 16-node tile. Lane l: node = r0+(l&15), col-groups (l>>4)*8+{0..7} and +32.
// Gathered f32 accumulators ARE the MFMA A-fragment (row=l&15, k=8*(l>>4)+j) after bf16 cast.
__global__ __launch_bounds__(256) void layer_fused_kernel(const int* __restrict__ ofs_i,
                                                          const int* __restrict__ ofs_u,
                                                          const int* __restrict__ by_dst,
                                                          const int* __restrict__ by_src,
                                                          const float* __restrict__ rs_u,
                                                          const float* __restrict__ rs_i,
                                                          const unsigned short* __restrict__ hu,
                                                          const unsigned short* __restrict__ hi,
                                                          const float* __restrict__ W1,
                                                          const float* __restrict__ b1,
                                                          const float* __restrict__ W2,
                                                          const float* __restrict__ b2,
                                                          unsigned short* __restrict__ hi_new,
                                                          unsigned short* __restrict__ hu_new) {
  const int lane = threadIdx.x & 63;
  const int row16 = lane & 15;
  const int kg = lane >> 4;  // 0..3
  const int wid = (blockIdx.x * 256 + threadIdx.x) >> 6;
  const int nwaves = (gridDim.x * 256) >> 6;

  // register-resident bf16 weight fragments (B-frag: col=lane&15 -> n, k=kg*8+j)
  bf16x8 w1f[4][2], w2f[4][2];
#pragma unroll
  for (int nb = 0; nb < 4; ++nb)
#pragma unroll
    for (int kb = 0; kb < 2; ++kb) {
      const int n = nb * 16 + row16;
      const int k0 = kb * 32 + kg * 8;
      bf16x8 t1, t2;
#pragma unroll
      for (int j = 0; j < 8; ++j) {
        t1[j] = f2bf(W1[(k0 + j) * 64 + n]);
        t2[j] = f2bf(W2[(k0 + j) * 64 + n]);
      }
      w1f[nb][kb] = t1;
      w2f[nb][kb] = t2;
    }
  float bsum[4];
#pragma unroll
  for (int nb = 0; nb < 4; ++nb) bsum[nb] = b1[nb * 16 + row16] + b2[nb * 16 + row16];

  for (int t = wid; t < NTI + NTU; t += nwaves) {
    const bool item = t < NTI;
    const int tt = item ? t : t - NTI;
    const int* ofs = item ? ofs_i : ofs_u;
    const int* pay = item ? by_dst : by_src;
    const float* rso = item ? rs_u : rs_i;   // neighbor weight
    const float* rsw = item ? rs_i : rs_u;   // own scale
    const unsigned short* hsrc = item ? hu : hi;
    const unsigned short* hold = item ? hi : hu;
    unsigned short* hnew = item ? hi_new : hu_new;
    const int r0 = tt * 16;
    const int node = r0 + row16;

    const int lo = ofs[node], hiE = ofs[node + 1];
    float a0[8] = {0.f, 0.f, 0.f, 0.f, 0.f, 0.f, 0.f, 0.f};
    float a1[8] = {0.f, 0.f, 0.f, 0.f, 0.f, 0.f, 0.f, 0.f};
    float cs = 0.f;
    for (int i = lo;; ++i) {
      const bool act = i < hiE;
      if (!__any(act)) break;
      if (act) {
        const int nb = pay[i];
        const float ww = rso[nb];
        const u16x8 h0 = *(const u16x8*)(hsrc + (size_t)nb * 64 + kg * 8);
        const u16x8 h1 = *(const u16x8*)(hsrc + (size_t)nb * 64 + kg * 8 + 32);
#pragma unroll
        for (int j = 0; j < 8; ++j) {
          a0[j] += ww * bf2f(h0[j]);
          a1[j] += ww * bf2f(h1[j]);
        }
        cs += ww;
      }
    }
    const float rsn = rsw[node];
    const u16x8 hv0 = *(const u16x8*)(hold + (size_t)node * 64 + kg * 8);
    const u16x8 hv1 = *(const u16x8*)(hold + (size_t)node * 64 + kg * 8 + 32);
    bf16x8 ag[2], ap[2];
#pragma unroll
    for (int j = 0; j < 8; ++j) {
      const float g0 = a0[j] * rsn;
      const float g1 = a1[j] * rsn;
      ag[0][j] = f2bf(g0);
      ag[1][j] = f2bf(g1);
      ap[0][j] = f2bf(g0 * bf2f(hv0[j]));
      ap[1][j] = f2bf(g1 * bf2f(hv1[j]));
    }
    const float csc = cs * rsn;

    f32x4 acc[4];
#pragma unroll
    for (int nb = 0; nb < 4; ++nb) acc[nb] = (f32x4){0.f, 0.f, 0.f, 0.f};
#pragma unroll
    for (int nb = 0; nb < 4; ++nb)
#pragma unroll
      for (int kb = 0; kb < 2; ++kb) {
        acc[nb] = __builtin_amdgcn_mfma_f32_16x16x32_bf16(ag[kb], w1f[nb][kb], acc[nb], 0, 0, 0);
        acc[nb] = __builtin_amdgcn_mfma_f32_16x16x32_bf16(ap[kb], w2f[nb][kb], acc[nb], 0, 0, 0);
      }
    // c for D-frag rows (row = kg*4+reg): fetch from the lane holding that node
    float cv[4];
#pragma unroll
    for (int reg = 0; reg < 4; ++reg) cv[reg] = __shfl(csc, kg * 4 + reg);
    float v[4][4];
    float ss[4] = {0.f, 0.f, 0.f, 0.f};
#pragma unroll
    for (int nb = 0; nb < 4; ++nb)
#pragma unroll
      for (int reg = 0; reg < 4; ++reg) {
        float x = acc[nb][reg] + cv[reg] * bsum[nb];
        x = (x > 0.f) ? x : 0.2f * x;
        v[nb][reg] = x;
        ss[reg] += x * x;
      }
#pragma unroll
    for (int m = 1; m < 16; m <<= 1)
#pragma unroll
      for (int reg = 0; reg < 4; ++reg) ss[reg] += __shfl_xor(ss[reg], m);
    float inv[4];
#pragma unroll
    for (int reg = 0; reg < 4; ++reg) inv[reg] = 1.0f / fmaxf(sqrtf(ss[reg]), 1e-12f);
#pragma unroll
    for (int reg = 0; reg < 4; ++reg) {
      const size_t rowbase = (size_t)(r0 + kg * 4 + reg) * 64;
#pragma unroll
      for (int nb = 0; nb < 4; ++nb)
        hnew[rowbase + nb * 16 + row16] = (unsigned short)f2bf(v[nb][reg] * inv[reg]);
    }
  }
}

// ================= output gathers =================
__global__ __launch_bounds__(256) void gather_f32_kernel(const float* __restrict__ hu,
                                                         const float* __restrict__ hi,
                                                         const int* __restrict__ users,
                                                         const int* __restrict__ pos,
                                                         const int* __restrict__ neg,
                                                         float* __restrict__ out) {
  int t = blockIdx.x * 256 + threadIdx.x;
  if (t >= 3 * NB * 64) return;
  int j = t & 63;
  int b = (t >> 6) & (NB - 1);
  int which = t / (NB * 64);
  int row = (which == 0) ? users[b] : ((which == 1) ? pos[b] : neg[b]);
  const float* h = (which == 0) ? hu : hi;
  out[(size_t)which * NB * 256 + (size_t)b * 256 + j] = h[(size_t)row * 64 + j];
}

__global__ __launch_bounds__(256) void gather_bf_kernel(const unsigned short* __restrict__ hu,
                                                        const unsigned short* __restrict__ hi,
                                                        const int* __restrict__ users,
                                                        const int* __restrict__ pos,
                                                        const int* __restrict__ neg,
                                                        float* __restrict__ out, int stage) {
  int t = blockIdx.x * 256 + threadIdx.x;
  if (t >= 3 * NB * 64) return;
  int j = t & 63;
  int b = (t >> 6) & (NB - 1);
  int which = t / (NB * 64);
  int row = (which == 0) ? users[b] : ((which == 1) ? pos[b] : neg[b]);
  const unsigned short* h = (which == 0) ? hu : hi;
  out[(size_t)which * NB * 256 + (size_t)b * 256 + (size_t)stage * 64 + j] =
      bf2f(h[(size_t)row * 64 + j]);
}

extern "C" void kernel_launch(void* const* d_in, const int* in_sizes, int n_in,
                              void* d_out, int out_size, void* d_ws, size_t ws_size,
                              hipStream_t stream) {
  (void)in_sizes; (void)n_in; (void)out_size; (void)ws_size;
  const float* user_feat = (const float*)d_in[0];
  const float* item_feat = (const float*)d_in[1];
  const float* W1 = (const float*)d_in[2];
  const float* b1 = (const float*)d_in[3];
  const float* W2 = (const float*)d_in[4];
  const float* b2 = (const float*)d_in[5];
  const int* edge_src = (const int*)d_in[6];
  const int* edge_dst = (const int*)d_in[7];
  const int* users = (const int*)d_in[8];
  const int* pos_items = (const int*)d_in[9];
  const int* neg_items = (const int*)d_in[10];
  float* out = (float*)d_out;

  char* base = (char*)d_ws;
  size_t ofsz = 0;
  auto alloc = [&](size_t bytes) -> char* {
    char* r = base + ofsz;
    ofsz += (bytes + 1023) & ~(size_t)1023;
    return r;
  };
  int* ofs_u = (int*)alloc((NU + 1) * 4);
  int* ofs_i = (int*)alloc((NI + 1) * 4);
  int* gcur_s = (int*)alloc(128 * 4);
  int* gcur_d = (int*)alloc(128 * 4);
  int* bktofs_s = (int*)alloc(128 * 4);
  int* bktofs_d = (int*)alloc(128 * 4);
  int2* temp_s = (int2*)alloc((size_t)NBS * CAP * 8);
  int2* temp_d = (int2*)alloc((size_t)NBD * CAP * 8);
  int* by_src = (int*)alloc((size_t)NE * 4);
  int* by_dst = (int*)alloc((size_t)NE * 4);
  float* rs_u = (float*)alloc((size_t)NU * 4);
  float* rs_i = (float*)alloc((size_t)NI * 4);
  unsigned short* hbU0 = (unsigned short*)alloc((size_t)NU * 64 * 2);
  unsigned short* hbU1 = (unsigned short*)alloc((size_t)NU * 64 * 2);
  unsigned short* hbI0 = (unsigned short*)alloc((size_t)NI * 64 * 2);
  unsigned short* hbI1 = (unsigned short*)alloc((size_t)NI * 64 * 2);

  unsigned short* bufU[2] = {hbU1, hbU0};
  unsigned short* bufI[2] = {hbI1, hbI0};

  hipMemsetAsync(gcur_s, 0, 128 * 4, stream);
  hipMemsetAsync(gcur_d, 0, 128 * 4, stream);
  binA_kernel<<<1024, 256, 0, stream>>>(edge_src, edge_dst, gcur_s, gcur_d, temp_s, temp_d);
  bktscan_kernel<<<1, 64, 0, stream>>>(gcur_s, gcur_d, bktofs_s, bktofs_d, ofs_u, ofs_i);
  placeB_kernel<<<NBS + NBD, 256, 0, stream>>>(temp_s, temp_d, gcur_s, gcur_d,
                                               bktofs_s, bktofs_d, ofs_u, ofs_i,
                                               rs_u, rs_i, by_src, by_dst);

  conv_kernel<<<((NU + NI) * 16 + 255) / 256, 256, 0, stream>>>(user_feat, item_feat, hbU0, hbI0);

  gather_f32_kernel<<<(3 * NB * 64 + 255) / 256, 256, 0, stream>>>(
      user_feat, item_feat, users, pos_items, neg_items, out);

  const unsigned short* hu = hbU0;
  const unsigned short* hi = hbI0;
  for (int l = 0; l < 3; ++l) {
    unsigned short* hu_new = bufU[l & 1];
    unsigned short* hi_new = bufI[l & 1];
    layer_fused_kernel<<<1024, 256, 0, stream>>>(ofs_i, ofs_u, by_dst, by_src,
                                                 rs_u, rs_i, hu, hi,
                                                 W1 + l * 4096, b1 + l * 64,
                                                 W2 + l * 4096, b2 + l * 64,
                                                 hi_new, hu_new);
    gather_bf_kernel<<<(3 * NB * 64 + 255) / 256, 256, 0, stream>>>(
        hu_new, hi_new, users, pos_items, neg_items, out, l + 1);
    hu = hu_new;
    hi = hi_new;
  }
}